// Round 9
// baseline (132.394 us; speedup 1.0000x reference)
//
#include <hip/hip_runtime.h>
#include <hip/hip_bf16.h>

typedef __bf16 bf16x8 __attribute__((ext_vector_type(8)));
typedef __bf16 bf16x4 __attribute__((ext_vector_type(4)));
typedef float  f32x4  __attribute__((ext_vector_type(4)));
typedef float  flt4v  __attribute__((ext_vector_type(4)));

#define ALPHA 0.2f
// B=8, N=2048, D=128. Inputs: h,W,a f32; adj int32. Output f32.

// Kernel P: pack adj (int32 0/1) into 1 bit/edge via wave ballot.
// chunk c covers adj[c*64 .. c*64+64) -> msk[c] (u64). 128 MB -> 4 MB.
__global__ __launch_bounds__(256) void adj_pack(
    const int* __restrict__ adj,             // [8*2048*2048]
    unsigned long long* __restrict__ msk)    // [8*2048*32]
{
    const int tid  = threadIdx.x;
    const int lane = tid & 63;
    const int wid  = (blockIdx.x * 256 + tid) >> 6;
    const int nw   = (gridDim.x * 256) >> 6;
    for (int c = wid; c < 524288; c += nw) {
        int v = adj[(size_t)c * 64 + lane];
        unsigned long long m = __ballot(v != 0);
        if (lane == 0) msk[c] = m;
    }
}

// Kernel A: Wh = bf16(h) @ bf16(W) via MFMA 16x16x32, stored TRANSPOSED wht[b][col][n] (bf16).
// Scores s_src/s_dst computed in PURE f32 as h · (W @ a).
__global__ __launch_bounds__(256) void gat_wh(
    const float* __restrict__ h,    // [8][2048][128] f32
    const float* __restrict__ W,    // [128][128] f32
    const float* __restrict__ a,    // [256] f32
    __bf16* __restrict__ wht,       // [8][128][2048] bf16
    float* __restrict__ ssrc,       // [8*2048]
    float* __restrict__ sdst)       // [8*2048]
{
    __shared__ __bf16 Wt[128][136];       // W transposed (bf16), padded
    __shared__ float wvs[128], wvd[128];  // W @ a_src, W @ a_dst (f32)
    const int tid = threadIdx.x;
    if (tid < 128) {
        float s0 = 0.f, s1 = 0.f;
        const float* wr = W + tid * 128;
        #pragma unroll 4
        for (int e = 0; e < 128; ++e) {
            float w = wr[e];
            s0 += w * a[e];
            s1 += w * a[128 + e];
        }
        wvs[tid] = s0; wvd[tid] = s1;
    }
    #pragma unroll
    for (int it = 0; it < 8; ++it) {
        int o = (it * 256 + tid) * 8;            // element offset in W
        flt4v v0 = *reinterpret_cast<const flt4v*>(W + o);
        flt4v v1 = *reinterpret_cast<const flt4v*>(W + o + 4);
        int d = o >> 7, e = o & 127;             // d = row(k), e = col base
        #pragma unroll
        for (int j = 0; j < 4; ++j) {
            Wt[e + j][d]     = (__bf16)v0[j];
            Wt[e + 4 + j][d] = (__bf16)v1[j];
        }
    }
    __syncthreads();
    const int wave = tid >> 6, lane = tid & 63;
    const int lr = lane & 15, lg = lane >> 4;
    const int row0 = blockIdx.x * 64 + wave * 16;   // flattened (b*2048+n) row base
    f32x4 acc[8];
    #pragma unroll
    for (int ct = 0; ct < 8; ++ct) acc[ct] = (f32x4){0.f, 0.f, 0.f, 0.f};
    #pragma unroll
    for (int kk = 0; kk < 4; ++kk) {
        const float* hp = h + (size_t)(row0 + lr) * 128 + kk * 32 + lg * 8;
        flt4v h0 = *reinterpret_cast<const flt4v*>(hp);
        flt4v h1 = *reinterpret_cast<const flt4v*>(hp + 4);
        bf16x8 af;
        #pragma unroll
        for (int j = 0; j < 4; ++j) { af[j] = (__bf16)h0[j]; af[4 + j] = (__bf16)h1[j]; }
        #pragma unroll
        for (int ct = 0; ct < 8; ++ct) {
            bf16x8 bf_ = *reinterpret_cast<const bf16x8*>(&Wt[ct * 16 + lr][kk * 32 + lg * 8]);
            acc[ct] = __builtin_amdgcn_mfma_f32_16x16x32_bf16(af, bf_, acc[ct], 0, 0, 0);
        }
    }
    const int b  = row0 >> 11;
    const int n0 = row0 & 2047;
    __bf16* wb = wht + (size_t)b * 128 * 2048;
    #pragma unroll
    for (int ct = 0; ct < 8; ++ct) {
        bf16x4 v;
        #pragma unroll
        for (int q = 0; q < 4; ++q) v[q] = (__bf16)acc[ct][q];
        *reinterpret_cast<bf16x4*>(wb + (ct * 16 + lr) * 2048 + n0 + lg * 4) = v;
    }
    const float* hrow = h + (size_t)(row0 + lr) * 128 + lg * 32;
    float s0 = 0.f, s1 = 0.f;
    #pragma unroll
    for (int u = 0; u < 32; u += 4) {
        flt4v hv = *reinterpret_cast<const flt4v*>(hrow + u);
        #pragma unroll
        for (int q = 0; q < 4; ++q) {
            float x = hv[q];
            s0 += x * wvs[lg * 32 + u + q];
            s1 += x * wvd[lg * 32 + u + q];
        }
    }
    s0 += __shfl_xor(s0, 16, 64); s0 += __shfl_xor(s0, 32, 64);
    s1 += __shfl_xor(s1, 16, 64); s1 += __shfl_xor(s1, 32, 64);
    if (lg == 0) {
        ssrc[row0 + lr] = s0;
        sdst[row0 + lr] = s1;
    }
}

// Kernel C: fused masked-softmax attention + PV. Output f32.
// Grid: 512 blocks; bid&7 = batch (XCD pinning: per-XCD hot set = wht[b] 512KB +
// msk[b] 512KB, L2-resident), bid>>3 = 32-row tile. Block: 512 thr = 8 waves:
// wave>>2 = row-group (16 rows), wave&3 = j-slice. Sibling waves (same slice,
// other group) read identical wht B-frags -> L1 dedup -> 256 MB L2 traffic total.
__global__ __launch_bounds__(512) void gat_attn(
    const unsigned long long* __restrict__ msk, // [8*2048][32] u64 bitmask
    const __bf16* __restrict__ wht,             // [8][128][2048] bf16
    const float* __restrict__ ssrc,
    const float* __restrict__ sdst,
    float* __restrict__ out)                    // [8][2048][128] f32
{
    __shared__ float accsh[2][16][136];         // one buffer per row-group
    __shared__ float lsh[2][16];
    const int tid = threadIdx.x, wave = tid >> 6, lane = tid & 63;
    const int lr = lane & 15, lg = lane >> 4;
    const int g = wave >> 2, slot = wave & 3;
    const int b  = blockIdx.x & 7;              // XCD pinning
    const int i0 = (blockIdx.x >> 3) << 5;      // 32-row tile base
    const int row = i0 + g * 16 + lr;           // this lane's P-row
    const float si = ssrc[b * 2048 + row];
    const unsigned long long* mrow = msk + (size_t)(b * 2048 + row) * 32;
    const float* sd = sdst + b * 2048;
    const __bf16* wb = wht + (size_t)b * 128 * 2048;

    f32x4 acc[8];
    #pragma unroll
    for (int ct = 0; ct < 8; ++ct) acc[ct] = (f32x4){0.f, 0.f, 0.f, 0.f};
    float lpart = 0.f;

    for (int jt = slot; jt < 32; jt += 4) {
        const int j0 = jt * 64;
        const unsigned long long mw = mrow[jt];
        bf16x8 pf[2];
        #pragma unroll
        for (int kk = 0; kk < 2; ++kk) {
            const int jb = j0 + kk * 32 + lg * 8;   // this lane's 8 j's
            const unsigned int m8 = (unsigned int)(mw >> (kk * 32 + lg * 8)) & 0xffu;
            #pragma unroll
            for (int v = 0; v < 2; ++v) {
                flt4v sv = *reinterpret_cast<const flt4v*>(sd + jb + v * 4);
                #pragma unroll
                for (int u = 0; u < 4; ++u) {
                    float e = si + sv[u];
                    e = fmaxf(e, ALPHA * e);        // leaky_relu (slope<1)
                    float p = __expf(e);
                    p = (m8 & (1u << (v * 4 + u))) ? p : 0.f;
                    __bf16 pb = (__bf16)p;
                    lpart += (float)pb;             // denom matches bf16 numerator
                    pf[kk][v * 4 + u] = pb;
                }
            }
        }
        #pragma unroll
        for (int kk = 0; kk < 2; ++kk) {
            const int jb = j0 + kk * 32 + lg * 8;
            #pragma unroll
            for (int ct = 0; ct < 8; ++ct) {
                // B frag: B[k=lg*8+u][n=ct*16+lr] = wht[ct*16+lr][jb+u]
                bf16x8 bf_ = *reinterpret_cast<const bf16x8*>(wb + (ct * 16 + lr) * 2048 + jb);
                acc[ct] = __builtin_amdgcn_mfma_f32_16x16x32_bf16(pf[kk], bf_, acc[ct], 0, 0, 0);
            }
        }
    }
    // reduce l over the 4 lg-groups
    lpart += __shfl_xor(lpart, 16, 64);
    lpart += __shfl_xor(lpart, 32, 64);

    // merge: group g's 4 j-slice waves -> accsh[g], sequential by slot
    #pragma unroll
    for (int s = 0; s < 4; ++s) {
        if (slot == s) {
            if (s == 0) {
                #pragma unroll
                for (int ct = 0; ct < 8; ++ct)
                    #pragma unroll
                    for (int q = 0; q < 4; ++q)
                        accsh[g][lg * 4 + q][ct * 16 + lr] = acc[ct][q];
                if (lane < 16) lsh[g][lr] = lpart;
            } else {
                #pragma unroll
                for (int ct = 0; ct < 8; ++ct)
                    #pragma unroll
                    for (int q = 0; q < 4; ++q)
                        accsh[g][lg * 4 + q][ct * 16 + lr] += acc[ct][q];
                if (lane < 16) lsh[g][lr] += lpart;
            }
        }
        __syncthreads();
    }

    // write out (f32): thread t -> row t>>4 (0..31), cols (t&15)*8..+8
    const int r  = tid >> 4;
    const int c0 = (tid & 15) * 8;
    const int rg = r >> 4, rr = r & 15;
    const float l = lsh[rg][rr];
    float* ob = out + ((size_t)b * 2048 + i0 + r) * 128 + c0;
    flt4v o0, o1;
    #pragma unroll
    for (int u = 0; u < 4; ++u) {
        o0[u] = accsh[rg][rr][c0 + u] / l;
        o1[u] = accsh[rg][rr][c0 + 4 + u] / l;
    }
    *reinterpret_cast<flt4v*>(ob)     = o0;
    *reinterpret_cast<flt4v*>(ob + 4) = o1;
}

extern "C" void kernel_launch(void* const* d_in, const int* in_sizes, int n_in,
                              void* d_out, int out_size, void* d_ws, size_t ws_size,
                              hipStream_t stream)
{
    // Bind inputs by element count (all four sizes distinct); fall back to dict order.
    const float* h = nullptr; const int* adj = nullptr;
    const float* W = nullptr; const float* a = nullptr;
    for (int i = 0; i < n_in; ++i) {
        switch (in_sizes[i]) {
            case 2097152:  h   = (const float*)d_in[i]; break;  // 8*2048*128
            case 33554432: adj = (const int*)d_in[i];   break;  // 8*2048*2048
            case 16384:    W   = (const float*)d_in[i]; break;  // 128*128
            case 256:      a   = (const float*)d_in[i]; break;  // 2*128
        }
    }
    if (!h || !adj || !W || !a) {
        h   = (const float*)d_in[0];
        adj = (const int*)d_in[1];
        W   = (const float*)d_in[2];
        a   = (const float*)d_in[3];
    }

    __bf16* wht = (__bf16*)d_ws;                                              // 4 MB
    unsigned long long* msk = (unsigned long long*)((char*)d_ws + (size_t)4*1024*1024); // 4 MB
    float* ssrc = (float*)((char*)d_ws + (size_t)8 * 1024 * 1024);            // 64 KB
    float* sdst = ssrc + 8 * 2048;                                            // 64 KB

    adj_pack<<<1024, 256, 0, stream>>>(adj, msk);
    gat_wh<<<256, 256, 0, stream>>>(h, W, a, wht, ssrc, sdst);
    gat_attn<<<512, 512, 0, stream>>>(msk, wht, ssrc, sdst, (float*)d_out);
}

// Round 10
// 108.530 us; speedup vs baseline: 1.2199x; 1.2199x over previous
//
#include <hip/hip_runtime.h>
#include <hip/hip_bf16.h>

typedef __bf16 bf16x8 __attribute__((ext_vector_type(8)));
typedef __bf16 bf16x4 __attribute__((ext_vector_type(4)));
typedef float  f32x4  __attribute__((ext_vector_type(4)));
typedef float  flt4v  __attribute__((ext_vector_type(4)));
typedef int    int4v  __attribute__((ext_vector_type(4)));

#define ALPHA 0.2f
// B=8, N=2048, D=128. Inputs: h,W,a f32; adj int32. Output f32.

// spread 16 bits so bit m -> bit 4m (for bit-plane -> chunk-word transpose)
__device__ __forceinline__ unsigned long long spread4(unsigned long long x) {
    x &= 0xFFFFull;
    x = (x | (x << 24)) & 0x000000FF000000FFull;
    x = (x | (x << 12)) & 0x000F000F000F000Full;
    x = (x | (x << 6))  & 0x0303030303030303ull;
    x = (x | (x << 3))  & 0x1111111111111111ull;
    return x;
}

// Kernel P: pack adj (int32 0/1) -> 1 bit/edge. msk[c] bit j = adj[c*64+j].
// 16 B/lane loads: wave processes 4 chunks (1 KB) per iteration, 16 iterations.
__global__ __launch_bounds__(256) void adj_pack(
    const int* __restrict__ adj,             // [8*2048*2048]
    unsigned long long* __restrict__ msk)    // [8*2048*32]
{
    const int tid  = threadIdx.x;
    const int lane = tid & 63;
    const int wid  = (blockIdx.x * 256 + tid) >> 6;   // global wave id (8192 waves)
    const int g0   = wid * 16;                        // 16 groups of 4 chunks each
    #pragma unroll 4
    for (int it = 0; it < 16; ++it) {
        const int g = g0 + it;                        // group = 4 chunks = 256 ints
        int4v v = *reinterpret_cast<const int4v*>(adj + (size_t)g * 256 + lane * 4);
        unsigned long long b0 = __ballot(v[0] != 0);  // bit i = element 4i+0
        unsigned long long b1 = __ballot(v[1] != 0);
        unsigned long long b2 = __ballot(v[2] != 0);
        unsigned long long b3 = __ballot(v[3] != 0);
        if (lane < 4) {
            const int k = lane;                       // chunk within group
            unsigned long long w =  spread4(b0 >> (16 * k))
                                 | (spread4(b1 >> (16 * k)) << 1)
                                 | (spread4(b2 >> (16 * k)) << 2)
                                 | (spread4(b3 >> (16 * k)) << 3);
            msk[(size_t)g * 4 + k] = w;
        }
    }
}

// Kernel A: Wh = bf16(h) @ bf16(W) via MFMA 16x16x32, stored TRANSPOSED wht[b][col][n] (bf16).
// Scores s_src/s_dst computed in PURE f32 as h · (W @ a).
__global__ __launch_bounds__(256) void gat_wh(
    const float* __restrict__ h,    // [8][2048][128] f32
    const float* __restrict__ W,    // [128][128] f32
    const float* __restrict__ a,    // [256] f32
    __bf16* __restrict__ wht,       // [8][128][2048] bf16
    float* __restrict__ ssrc,       // [8*2048]
    float* __restrict__ sdst)       // [8*2048]
{
    __shared__ __bf16 Wt[128][136];       // W transposed (bf16), padded
    __shared__ float wvs[128], wvd[128];  // W @ a_src, W @ a_dst (f32)
    const int tid = threadIdx.x;
    if (tid < 128) {
        float s0 = 0.f, s1 = 0.f;
        const float* wr = W + tid * 128;
        #pragma unroll 4
        for (int e = 0; e < 128; ++e) {
            float w = wr[e];
            s0 += w * a[e];
            s1 += w * a[128 + e];
        }
        wvs[tid] = s0; wvd[tid] = s1;
    }
    #pragma unroll
    for (int it = 0; it < 8; ++it) {
        int o = (it * 256 + tid) * 8;            // element offset in W
        flt4v v0 = *reinterpret_cast<const flt4v*>(W + o);
        flt4v v1 = *reinterpret_cast<const flt4v*>(W + o + 4);
        int d = o >> 7, e = o & 127;             // d = row(k), e = col base
        #pragma unroll
        for (int j = 0; j < 4; ++j) {
            Wt[e + j][d]     = (__bf16)v0[j];
            Wt[e + 4 + j][d] = (__bf16)v1[j];
        }
    }
    __syncthreads();
    const int wave = tid >> 6, lane = tid & 63;
    const int lr = lane & 15, lg = lane >> 4;
    const int row0 = blockIdx.x * 64 + wave * 16;   // flattened (b*2048+n) row base
    f32x4 acc[8];
    #pragma unroll
    for (int ct = 0; ct < 8; ++ct) acc[ct] = (f32x4){0.f, 0.f, 0.f, 0.f};
    #pragma unroll
    for (int kk = 0; kk < 4; ++kk) {
        const float* hp = h + (size_t)(row0 + lr) * 128 + kk * 32 + lg * 8;
        flt4v h0 = *reinterpret_cast<const flt4v*>(hp);
        flt4v h1 = *reinterpret_cast<const flt4v*>(hp + 4);
        bf16x8 af;
        #pragma unroll
        for (int j = 0; j < 4; ++j) { af[j] = (__bf16)h0[j]; af[4 + j] = (__bf16)h1[j]; }
        #pragma unroll
        for (int ct = 0; ct < 8; ++ct) {
            bf16x8 bf_ = *reinterpret_cast<const bf16x8*>(&Wt[ct * 16 + lr][kk * 32 + lg * 8]);
            acc[ct] = __builtin_amdgcn_mfma_f32_16x16x32_bf16(af, bf_, acc[ct], 0, 0, 0);
        }
    }
    const int b  = row0 >> 11;
    const int n0 = row0 & 2047;
    __bf16* wb = wht + (size_t)b * 128 * 2048;
    #pragma unroll
    for (int ct = 0; ct < 8; ++ct) {
        bf16x4 v;
        #pragma unroll
        for (int q = 0; q < 4; ++q) v[q] = (__bf16)acc[ct][q];
        *reinterpret_cast<bf16x4*>(wb + (ct * 16 + lr) * 2048 + n0 + lg * 4) = v;
    }
    const float* hrow = h + (size_t)(row0 + lr) * 128 + lg * 32;
    float s0 = 0.f, s1 = 0.f;
    #pragma unroll
    for (int u = 0; u < 32; u += 4) {
        flt4v hv = *reinterpret_cast<const flt4v*>(hrow + u);
        #pragma unroll
        for (int q = 0; q < 4; ++q) {
            float x = hv[q];
            s0 += x * wvs[lg * 32 + u + q];
            s1 += x * wvd[lg * 32 + u + q];
        }
    }
    s0 += __shfl_xor(s0, 16, 64); s0 += __shfl_xor(s0, 32, 64);
    s1 += __shfl_xor(s1, 16, 64); s1 += __shfl_xor(s1, 32, 64);
    if (lg == 0) {
        ssrc[row0 + lr] = s0;
        sdst[row0 + lr] = s1;
    }
}

// Kernel C: fused masked-softmax attention + PV. Output f32.
// Grid: 512 blocks; bid&7 = batch (XCD pinning), bid>>3 = 32-row tile.
// Block: 512 thr = 8 waves: wave>>2 = row-group (16 rows), wave&3 = j-slice.
__global__ __launch_bounds__(512) void gat_attn(
    const unsigned long long* __restrict__ msk, // [8*2048][32] u64 bitmask
    const __bf16* __restrict__ wht,             // [8][128][2048] bf16
    const float* __restrict__ ssrc,
    const float* __restrict__ sdst,
    float* __restrict__ out)                    // [8][2048][128] f32
{
    __shared__ float accsh[2][16][136];         // one buffer per row-group
    __shared__ float lsh[2][16];
    const int tid = threadIdx.x, wave = tid >> 6, lane = tid & 63;
    const int lr = lane & 15, lg = lane >> 4;
    const int g = wave >> 2, slot = wave & 3;
    const int b  = blockIdx.x & 7;              // XCD pinning
    const int i0 = (blockIdx.x >> 3) << 5;      // 32-row tile base
    const int row = i0 + g * 16 + lr;           // this lane's P-row
    const float si = ssrc[b * 2048 + row];
    const unsigned long long* mrow = msk + (size_t)(b * 2048 + row) * 32;
    const float* sd = sdst + b * 2048;
    const __bf16* wb = wht + (size_t)b * 128 * 2048;

    f32x4 acc[8];
    #pragma unroll
    for (int ct = 0; ct < 8; ++ct) acc[ct] = (f32x4){0.f, 0.f, 0.f, 0.f};
    float lpart = 0.f;

    for (int jt = slot; jt < 32; jt += 4) {
        const int j0 = jt * 64;
        const unsigned long long mw = mrow[jt];
        bf16x8 pf[2];
        #pragma unroll
        for (int kk = 0; kk < 2; ++kk) {
            const int jb = j0 + kk * 32 + lg * 8;   // this lane's 8 j's
            const unsigned int m8 = (unsigned int)(mw >> (kk * 32 + lg * 8)) & 0xffu;
            #pragma unroll
            for (int v = 0; v < 2; ++v) {
                flt4v sv = *reinterpret_cast<const flt4v*>(sd + jb + v * 4);
                #pragma unroll
                for (int u = 0; u < 4; ++u) {
                    float e = si + sv[u];
                    e = fmaxf(e, ALPHA * e);        // leaky_relu (slope<1)
                    float p = __expf(e);
                    p = (m8 & (1u << (v * 4 + u))) ? p : 0.f;
                    __bf16 pb = (__bf16)p;
                    lpart += (float)pb;             // denom matches bf16 numerator
                    pf[kk][v * 4 + u] = pb;
                }
            }
        }
        #pragma unroll
        for (int kk = 0; kk < 2; ++kk) {
            const int jb = j0 + kk * 32 + lg * 8;
            #pragma unroll
            for (int ct = 0; ct < 8; ++ct) {
                // B frag: B[k=lg*8+u][n=ct*16+lr] = wht[ct*16+lr][jb+u]
                bf16x8 bf_ = *reinterpret_cast<const bf16x8*>(wb + (ct * 16 + lr) * 2048 + jb);
                acc[ct] = __builtin_amdgcn_mfma_f32_16x16x32_bf16(pf[kk], bf_, acc[ct], 0, 0, 0);
            }
        }
    }
    // reduce l over the 4 lg-groups
    lpart += __shfl_xor(lpart, 16, 64);
    lpart += __shfl_xor(lpart, 32, 64);

    // merge: group g's 4 j-slice waves -> accsh[g], sequential by slot
    #pragma unroll
    for (int s = 0; s < 4; ++s) {
        if (slot == s) {
            if (s == 0) {
                #pragma unroll
                for (int ct = 0; ct < 8; ++ct)
                    #pragma unroll
                    for (int q = 0; q < 4; ++q)
                        accsh[g][lg * 4 + q][ct * 16 + lr] = acc[ct][q];
                if (lane < 16) lsh[g][lr] = lpart;
            } else {
                #pragma unroll
                for (int ct = 0; ct < 8; ++ct)
                    #pragma unroll
                    for (int q = 0; q < 4; ++q)
                        accsh[g][lg * 4 + q][ct * 16 + lr] += acc[ct][q];
                if (lane < 16) lsh[g][lr] += lpart;
            }
        }
        __syncthreads();
    }

    // write out (f32): thread t -> row t>>4 (0..31), cols (t&15)*8..+8
    const int r  = tid >> 4;
    const int c0 = (tid & 15) * 8;
    const int rg = r >> 4, rr = r & 15;
    const float l = lsh[rg][rr];
    float* ob = out + ((size_t)b * 2048 + i0 + r) * 128 + c0;
    flt4v o0, o1;
    #pragma unroll
    for (int u = 0; u < 4; ++u) {
        o0[u] = accsh[rg][rr][c0 + u] / l;
        o1[u] = accsh[rg][rr][c0 + 4 + u] / l;
    }
    *reinterpret_cast<flt4v*>(ob)     = o0;
    *reinterpret_cast<flt4v*>(ob + 4) = o1;
}

extern "C" void kernel_launch(void* const* d_in, const int* in_sizes, int n_in,
                              void* d_out, int out_size, void* d_ws, size_t ws_size,
                              hipStream_t stream)
{
    // Bind inputs by element count (all four sizes distinct); fall back to dict order.
    const float* h = nullptr; const int* adj = nullptr;
    const float* W = nullptr; const float* a = nullptr;
    for (int i = 0; i < n_in; ++i) {
        switch (in_sizes[i]) {
            case 2097152:  h   = (const float*)d_in[i]; break;  // 8*2048*128
            case 33554432: adj = (const int*)d_in[i];   break;  // 8*2048*2048
            case 16384:    W   = (const float*)d_in[i]; break;  // 128*128
            case 256:      a   = (const float*)d_in[i]; break;  // 2*128
        }
    }
    if (!h || !adj || !W || !a) {
        h   = (const float*)d_in[0];
        adj = (const int*)d_in[1];
        W   = (const float*)d_in[2];
        a   = (const float*)d_in[3];
    }

    __bf16* wht = (__bf16*)d_ws;                                              // 4 MB
    unsigned long long* msk = (unsigned long long*)((char*)d_ws + (size_t)4*1024*1024); // 4 MB
    float* ssrc = (float*)((char*)d_ws + (size_t)8 * 1024 * 1024);            // 64 KB
    float* sdst = ssrc + 8 * 2048;                                            // 64 KB

    adj_pack<<<2048, 256, 0, stream>>>(adj, msk);
    gat_wh<<<256, 256, 0, stream>>>(h, W, a, wht, ssrc, sdst);
    gat_attn<<<512, 512, 0, stream>>>(msk, wht, ssrc, sdst, (float*)d_out);
}